// Round 2
// baseline (557.496 us; speedup 1.0000x reference)
//
#include <hip/hip_runtime.h>

#define D_DIM 2048
#define E_NUM 64
#define M_TOK 16384          // B*L = 4*4096
#define BM 64

// ws layout: part [nsplit][M_TOK][E_NUM] f32, then blockp[256][64], blockc[256][64]

// ---------------- GEMM: no LDS, stream x/W from global, 4x4 frag ----------------
// 256 thr: ty=tid>>4 (16 token-quads -> 64 tokens), tx=tid&15 (16 expert-quads -> 64 experts)
// x rows broadcast across the 16 tx-lanes (coalescer merges same-address); W rows L1/L2-hot.
__global__ __launch_bounds__(256, 4) void gemm_kernel(
    const float* __restrict__ x, const float* __restrict__ W,
    float* __restrict__ part, int ksplit)
{
    const int tid = threadIdx.x;
    const int tx  = tid & 15;
    const int ty  = tid >> 4;
    const long tokbase = (long)blockIdx.x * BM;
    const int  kbase   = blockIdx.y * ksplit;

    const float* xp[4];
    const float* wp[4];
    #pragma unroll
    for (int i = 0; i < 4; ++i) {
        xp[i] = x + (tokbase + (long)(ty * 4 + i)) * D_DIM + kbase;
        wp[i] = W + (long)(tx * 4 + i) * D_DIM + kbase;
    }

    double accd[4][4];
    #pragma unroll
    for (int i = 0; i < 4; ++i)
        #pragma unroll
        for (int j = 0; j < 4; ++j) accd[i][j] = 0.0;

    for (int kc = 0; kc < ksplit; kc += 32) {
        float accc[4][4];
        #pragma unroll
        for (int i = 0; i < 4; ++i)
            #pragma unroll
            for (int j = 0; j < 4; ++j) accc[i][j] = 0.0f;

        #pragma unroll
        for (int kb = 0; kb < 8; ++kb) {
            const int ko = kc + kb * 4;
            float4 xv[4], wv[4];
            #pragma unroll
            for (int i = 0; i < 4; ++i) xv[i] = *(const float4*)(xp[i] + ko);
            #pragma unroll
            for (int j = 0; j < 4; ++j) wv[j] = *(const float4*)(wp[j] + ko);
            #pragma unroll
            for (int i = 0; i < 4; ++i)
                #pragma unroll
                for (int j = 0; j < 4; ++j) {
                    accc[i][j] += xv[i].x * wv[j].x;
                    accc[i][j] += xv[i].y * wv[j].y;
                    accc[i][j] += xv[i].z * wv[j].z;
                    accc[i][j] += xv[i].w * wv[j].w;
                }
        }
        // fold fp32 chunk -> fp64 every 32 k (keeps index-exact accuracy)
        #pragma unroll
        for (int i = 0; i < 4; ++i)
            #pragma unroll
            for (int j = 0; j < 4; ++j) accd[i][j] += (double)accc[i][j];
    }

    float* dst = part + (size_t)blockIdx.y * ((size_t)M_TOK * E_NUM);
    #pragma unroll
    for (int i = 0; i < 4; ++i) {
        const long m = tokbase + ty * 4 + i;
        float4 v;
        v.x = (float)accd[i][0]; v.y = (float)accd[i][1];
        v.z = (float)accd[i][2]; v.w = (float)accd[i][3];
        *(float4*)&dst[m * E_NUM + (tx << 2)] = v;
    }
}

// ---------------- top-k: thread-per-token, register scan, no shuffles ----------------
__global__ __launch_bounds__(64) void topk_kernel(
    const float* __restrict__ part, float* __restrict__ out,
    float* __restrict__ blockp, float* __restrict__ blockc, int nsplit)
{
    __shared__ float red[64 * 68];   // [lane][e], stride 68 keeps b128 align + odd-ish banks
    __shared__ int   i1s[64];
    const int  lane = threadIdx.x;
    const long t    = (long)blockIdx.x * 64 + lane;

    float l[64];
    #pragma unroll
    for (int j = 0; j < 16; ++j) {
        const float4 v = *(const float4*)&part[t * E_NUM + j * 4];
        l[j * 4 + 0] = v.x; l[j * 4 + 1] = v.y; l[j * 4 + 2] = v.z; l[j * 4 + 3] = v.w;
    }
    for (int s = 1; s < nsplit; ++s) {
        #pragma unroll
        for (int j = 0; j < 16; ++j) {
            const float4 v = *(const float4*)&part[((size_t)s * M_TOK + t) * E_NUM + j * 4];
            l[j * 4 + 0] += v.x; l[j * 4 + 1] += v.y; l[j * 4 + 2] += v.z; l[j * 4 + 3] += v.w;
        }
    }

    // top-2 with lowest-index tie-break (strict >, ascending scan) — matches lax.top_k
    float m1 = -1e30f, m2 = -1e30f; int i1 = 0, i2 = 0;
    #pragma unroll
    for (int e = 0; e < 64; ++e) {
        const float v = l[e];
        if (v > m1)      { m2 = m1; i2 = i1; m1 = v; i1 = e; }
        else if (v > m2) { m2 = v;  i2 = e; }
    }

    // full softmax (for aux loss)
    float ssum = 0.0f;
    #pragma unroll
    for (int e = 0; e < 64; ++e) { l[e] = __expf(l[e] - m1); ssum += l[e]; }
    const float inv = 1.0f / ssum;

    #pragma unroll
    for (int j = 0; j < 16; ++j) {
        float4 v;
        v.x = l[j * 4 + 0] * inv; v.y = l[j * 4 + 1] * inv;
        v.z = l[j * 4 + 2] * inv; v.w = l[j * 4 + 3] * inv;
        *(float4*)&red[lane * 68 + j * 4] = v;
    }
    i1s[lane] = i1;

    // per-token outputs
    float2 oi; oi.x = (float)i1; oi.y = (float)i2;
    *(float2*)&out[2 * t] = oi;
    const float w1 = 1.0f / (1.0f + __expf(m2 - m1));
    float2 ow; ow.x = w1; ow.y = 1.0f - w1;
    *(float2*)&out[2 * M_TOK + 2 * t] = ow;

    __syncthreads();
    // column reduction: thread e sums prob and top-1 count over the 64 tokens
    float P = 0.0f;
    #pragma unroll
    for (int lx = 0; lx < 64; ++lx) P += red[lx * 68 + lane];
    float C = 0.0f;
    #pragma unroll
    for (int lx = 0; lx < 64; ++lx) C += (i1s[lx] == lane) ? 1.0f : 0.0f;
    blockp[blockIdx.x * E_NUM + lane] = P;
    blockc[blockIdx.x * E_NUM + lane] = C;
}

// ---------------- aux reduction ----------------
__global__ __launch_bounds__(64) void aux_kernel(
    const float* __restrict__ blockp, const float* __restrict__ blockc,
    float* __restrict__ out)
{
    const int e = threadIdx.x;
    float P = 0.0f, C = 0.0f;
    for (int b = 0; b < 256; ++b) {
        P += blockp[b * E_NUM + e];
        C += blockc[b * E_NUM + e];
    }
    float v = P * C;
    #pragma unroll
    for (int off = 32; off > 0; off >>= 1) v += __shfl_xor(v, off, 64);
    if (e == 0)
        out[4 * M_TOK] = 64.0f * 0.01f * v / ((float)M_TOK * (float)M_TOK);
}

extern "C" void kernel_launch(void* const* d_in, const int* in_sizes, int n_in,
                              void* d_out, int out_size, void* d_ws, size_t ws_size,
                              hipStream_t stream)
{
    const float* x = (const float*)d_in[0];
    const float* W = (const float*)d_in[1];
    float* out = (float*)d_out;

    const size_t need4 = (size_t)4 * M_TOK * E_NUM * sizeof(float)
                       + (size_t)2 * 256 * E_NUM * sizeof(float);
    const int nsplit = (ws_size >= need4) ? 4 : 2;   // ws-size constant across calls
    const int ksplit = D_DIM / nsplit;

    float* part   = (float*)d_ws;
    float* blockp = part + (size_t)nsplit * M_TOK * E_NUM;
    float* blockc = blockp + 256 * E_NUM;

    gemm_kernel<<<dim3(M_TOK / BM, nsplit), 256, 0, stream>>>(x, W, part, ksplit);
    topk_kernel<<<256, 64, 0, stream>>>(part, out, blockp, blockc, nsplit);
    aux_kernel<<<1, 64, 0, stream>>>(blockp, blockc, out);
}